// Round 1
// baseline (487.816 us; speedup 1.0000x reference)
//
#include <hip/hip_runtime.h>

// CSR SpMV matching the JAX reference's searchsorted semantics:
//   out[0]   = sum_{j in [0,        off[1])}  vals[j]*x[col[j]]
//   out[r]   = sum_{j in [off[r],   off[r+1])} ...      (1 <= r < num_rows)
//   j >= off[num_rows] are dropped (never touched since we stop at off[num_rows]).
//
// 8 lanes cooperate per row (avg degree 32 -> ~4 iters/lane).

#define LANES_PER_ROW 8

__global__ void spmv_csr_vector(const float* __restrict__ vals,
                                const float* __restrict__ x,
                                const int*   __restrict__ col,
                                const int*   __restrict__ off,
                                float*       __restrict__ out,
                                int num_rows) {
    const int tid     = blockIdx.x * blockDim.x + threadIdx.x;
    const int group   = tid / LANES_PER_ROW;
    const int lane    = tid & (LANES_PER_ROW - 1);
    const int ngroups = (gridDim.x * blockDim.x) / LANES_PER_ROW;

    for (int r = group; r < num_rows; r += ngroups) {
        const int start = (r == 0) ? 0 : off[r];
        const int end   = off[r + 1];

        float sum = 0.0f;
        for (int j = start + lane; j < end; j += LANES_PER_ROW) {
            sum += vals[j] * x[col[j]];
        }

        // Reduce across the 8-lane group (group is aligned within the wave64).
        sum += __shfl_xor(sum, 1, 64);
        sum += __shfl_xor(sum, 2, 64);
        sum += __shfl_xor(sum, 4, 64);

        if (lane == 0) out[r] = sum;
    }
}

extern "C" void kernel_launch(void* const* d_in, const int* in_sizes, int n_in,
                              void* d_out, int out_size, void* d_ws, size_t ws_size,
                              hipStream_t stream) {
    const float* vals = (const float*)d_in[0];
    const float* x    = (const float*)d_in[1];
    const int*   col  = (const int*)d_in[2];
    const int*   off  = (const int*)d_in[3];
    float*       out  = (float*)d_out;

    const int num_rows = in_sizes[3] - 1;

    const int block = 256;
    // One 8-lane group per row would need num_rows*8 threads; grid-stride with
    // a full-size launch (31250 blocks for 1M rows) — launch overhead is tiny
    // relative to ~50us of memory traffic.
    long long total_threads = (long long)num_rows * LANES_PER_ROW;
    int grid = (int)((total_threads + block - 1) / block);
    if (grid > 65535 * 8) grid = 65535 * 8;  // safety clamp; loop handles rest

    spmv_csr_vector<<<grid, block, 0, stream>>>(vals, x, col, off, out, num_rows);
}